// Round 6
// baseline (40328.290 us; speedup 1.0000x reference)
//
#include <hip/hip_runtime.h>

#define T_TOK 1024
#define HD    2048
#define NE    64
#define ID    768
#define TOPK  8

typedef __bf16 bf16x8 __attribute__((ext_vector_type(8)));
typedef __bf16 bf16x4 __attribute__((ext_vector_type(4)));
typedef float  f32x4  __attribute__((ext_vector_type(4)));

#define LGKM0 asm volatile("s_waitcnt lgkmcnt(0)" ::: "memory")
#define BAR() __builtin_amdgcn_s_barrier()

__device__ __forceinline__ int swz(int r) { return (r ^ (r >> 2)) & 3; }

// ---------------------------------------------------------------------------
// Router: fp64 logits -> top-8 -> renormalized weights; per-expert lists;
// x -> bf16.
// ---------------------------------------------------------------------------
__global__ __launch_bounds__(256) void router_kernel(
    const float* __restrict__ x, const float* __restrict__ rw,
    unsigned short* __restrict__ xb_u, float* __restrict__ tw,
    int* __restrict__ counts, int* __restrict__ lists)
{
  __shared__ float  sx[HD];
  __shared__ double slog[NE];
  const int t = blockIdx.x;
  const int tid = threadIdx.x;
  __bf16* xb = (__bf16*)xb_u;

  for (int i = tid; i < HD; i += 256) {
    float v = x[(size_t)t * HD + i];
    sx[i] = v;
    xb[(size_t)t * HD + i] = (__bf16)v;
  }
  __syncthreads();

  const int e = tid >> 2, p = tid & 3;
  const float* rwrow = rw + (size_t)e * HD;
  double acc = 0.0;
  for (int k = p; k < HD; k += 4)
    acc += (double)sx[k] * (double)rwrow[k];
  acc += __shfl_xor(acc, 1, 64);
  acc += __shfl_xor(acc, 2, 64);
  if (p == 0) slog[e] = acc;
  __syncthreads();

  if (tid < 64) {
    double v = slog[tid];
    double selv = -1e300; int seli = 0; double gmax = 0.0;
    #pragma unroll
    for (int k = 0; k < TOPK; ++k) {
      double bv = v; int bi = tid;
      #pragma unroll
      for (int off = 32; off >= 1; off >>= 1) {
        double ov = __shfl_xor(bv, off, 64);
        int    oi = __shfl_xor(bi, off, 64);
        if (ov > bv || (ov == bv && oi < bi)) { bv = ov; bi = oi; }
      }
      if (k == 0) gmax = bv;
      if (tid == k) { selv = bv; seli = bi; }
      if (tid == bi) v = -1e300;
    }
    double e_ = (tid < TOPK) ? exp(selv - gmax) : 0.0;
    double s = e_;
    #pragma unroll
    for (int off = 32; off >= 1; off >>= 1) s += __shfl_xor(s, off, 64);
    if (tid < TOPK) {
      int slot = t * TOPK + tid;
      tw[slot] = (float)(e_ / s);
      int pos = atomicAdd(&counts[seli], 1);
      lists[seli * T_TOK + pos] = slot;
    }
  }
}

// ---------------------------------------------------------------------------
// GEMM1: BM=256, BN=64 (dual gate+up), BK=32, 512 thr (8 waves, 2Mx4N).
// Reg-staged double-buffer pipeline with TWO load generations per wave:
// step t: vmcnt(4) [gen t done, gen t+1 in flight] -> ds_write gen t ->
// issue gen t+2 into freed regs -> lgkmcnt(0)+s_barrier (loads NOT drained)
// -> ds_read frags -> MFMA. Exact counted tail.
// ---------------------------------------------------------------------------
__global__ __launch_bounds__(512, 4) void gemm1_kernel(
    const unsigned short* __restrict__ xb_u,
    const float* __restrict__ gw, const float* __restrict__ uw,
    const int* __restrict__ counts, const int* __restrict__ lists,
    unsigned short* __restrict__ hb_u)
{
  __shared__ __bf16 sA[2][256 * 32];   // [row][k] 64B rows, chunk-swizzled
  __shared__ __bf16 sG[2][64 * 32];
  __shared__ __bf16 sU[2][64 * 32];
  __shared__ int    sSlot[256];

  const __bf16* xb = (const __bf16*)xb_u;
  __bf16* hb = (__bf16*)hb_u;

  // 768 blocks = 8 XCD chunks of 96 (12 n-tiles x 8 experts per XCD chunk)
  const int wg  = blockIdx.x;
  const int idx = wg >> 3;
  const int e   = (wg & 7) * 8 + idx / 12;
  const int n0  = (idx % 12) * 64;
  const int tid = threadIdx.x, wid = tid >> 6, lane = tid & 63;
  const int mr = wid >> 2, nc = wid & 3;
  const int n_e = counts[e];

  // A staging: 2 ops/thread, rows wid*32 + {0,16} + (lane>>2)
  const int rA0 = wid * 32 + (lane >> 2);
  const int rA1 = rA0 + 16;
  const int cA  = lane & 3;
  const int aDst0 = rA0 * 64 + ((cA ^ swz(rA0)) << 4);
  const int aDst1 = rA1 * 64 + ((cA ^ swz(rA1)) << 4);

  // W staging: 1 f32x4/thread per matrix
  const int cW = tid >> 3, kc = tid & 7;
  const float* gSrc = gw + ((size_t)e * ID + n0 + cW) * HD + kc * 4;
  const float* uSrc = uw + ((size_t)e * ID + n0 + cW) * HD + kc * 4;
  const int wDst = cW * 64 + (((kc >> 1) ^ swz(cW)) << 4) + (kc & 1) * 8;

  // W frag geometry (per wave)
  const int colW  = nc * 16 + (lane & 15);
  const int wFoff = colW * 64 + (((lane >> 4) ^ swz(colW)) << 4);

#define G1_STEP(VML, BUF, A0, A1, GR, UR, KNXT, DOI)                              \
  {                                                                               \
    asm volatile("s_waitcnt vmcnt(" VML ")" ::: "memory");                        \
    char* bA = (char*)&sA[BUF][0];                                                \
    char* bG = (char*)&sG[BUF][0];                                                \
    char* bU = (char*)&sU[BUF][0];                                                \
    *(bf16x8*)(bA + aDst0) = A0;                                                  \
    *(bf16x8*)(bA + aDst1) = A1;                                                  \
    bf16x4 gv_, uv_;                                                              \
    _Pragma("unroll") for (int q = 0; q < 4; ++q) {                               \
      gv_[q] = (__bf16)GR[q]; uv_[q] = (__bf16)UR[q];                             \
    }                                                                             \
    *(bf16x4*)(bG + wDst) = gv_;                                                  \
    *(bf16x4*)(bU + wDst) = uv_;                                                  \
    if (DOI) {                                                                    \
      A0 = *(const bf16x8*)(aSrc0 + (KNXT));                                      \
      A1 = *(const bf16x8*)(aSrc1 + (KNXT));                                      \
      GR = *(const f32x4*)(gSrc + (KNXT));                                        \
      UR = *(const f32x4*)(uSrc + (KNXT));                                        \
    }                                                                             \
    LGKM0; BAR();                                                                 \
    __builtin_amdgcn_sched_barrier(0);                                            \
    bf16x8 gF_ = *(const bf16x8*)(bG + wFoff);                                    \
    bf16x8 uF_ = *(const bf16x8*)(bU + wFoff);                                    \
    _Pragma("unroll") for (int q = 0; q < 8; ++q) if (q * 16 < rows_here) {       \
      int row = mr * 128 + q * 16 + (lane & 15);                                  \
      bf16x8 aF_ = *(const bf16x8*)(bA + row * 64 + (((lane >> 4) ^ swz(row)) << 4)); \
      accg[q] = __builtin_amdgcn_mfma_f32_16x16x32_bf16(aF_, gF_, accg[q], 0, 0, 0);  \
      accu[q] = __builtin_amdgcn_mfma_f32_16x16x32_bf16(aF_, uF_, accu[q], 0, 0, 0);  \
    }                                                                             \
  }

  for (int m0 = 0; m0 < n_e; m0 += 256) {
    __syncthreads();   // full drain between passes
    if (tid < 256) sSlot[tid] = (m0 + tid < n_e) ? lists[e * T_TOK + m0 + tid] : 0;
    __syncthreads();

    const __bf16* aSrc0 = xb + (size_t)(sSlot[rA0] >> 3) * HD + cA * 8;
    const __bf16* aSrc1 = xb + (size_t)(sSlot[rA1] >> 3) * HD + cA * 8;

    f32x4 accg[8], accu[8];
    const f32x4 vzero = {0.f, 0.f, 0.f, 0.f};
    #pragma unroll
    for (int q = 0; q < 8; ++q) { accg[q] = vzero; accu[q] = vzero; }

    const int rows_here = n_e - m0 - mr * 128;   // wave-uniform

    // prologue: gen 0 -> set A (k=0), gen 1 -> set B (k=32)
    bf16x8 a0A = *(const bf16x8*)aSrc0;
    bf16x8 a1A = *(const bf16x8*)aSrc1;
    f32x4  gA  = *(const f32x4*)gSrc;
    f32x4  uA  = *(const f32x4*)uSrc;
    bf16x8 a0B = *(const bf16x8*)(aSrc0 + 32);
    bf16x8 a1B = *(const bf16x8*)(aSrc1 + 32);
    f32x4  gB  = *(const f32x4*)(gSrc + 32);
    f32x4  uB  = *(const f32x4*)(uSrc + 32);

    #pragma unroll 1
    for (int it = 0; it < 31; ++it) {                 // steps 0..61
      const int t = 2 * it;
      G1_STEP("4", 0, a0A, a1A, gA, uA, (t + 2) * 32, 1)
      G1_STEP("4", 1, a0B, a1B, gB, uB, (t + 3) * 32, 1)
    }
    G1_STEP("4", 0, a0A, a1A, gA, uA, 0, 0)           // step 62
    G1_STEP("0", 1, a0B, a1B, gB, uB, 0, 0)           // step 63

    // epilogue: silu(g)*u -> bf16 hidden_buf
    #pragma unroll
    for (int q = 0; q < 8; ++q) if (q * 16 < rows_here) {
      #pragma unroll
      for (int j = 0; j < 4; ++j) {
        int row = mr * 128 + q * 16 + (lane >> 4) * 4 + j;
        if (m0 + row < n_e) {
          int s = sSlot[row];
          float g = accg[q][j], u = accu[q][j];
          float h = (g / (1.0f + expf(-g))) * u;
          hb[(size_t)s * ID + (size_t)(n0 + colW)] = (__bf16)h;
        }
      }
    }
  }
#undef G1_STEP
}

// ---------------------------------------------------------------------------
// GEMM2: BM=256, BN=64 H-cols, BK=32, K=768 (24 steps). Same 2-generation
// pipeline (3 loads/gen -> vmcnt(3)); weighted atomic scatter to out.
// ---------------------------------------------------------------------------
__global__ __launch_bounds__(512, 4) void gemm2_kernel(
    const unsigned short* __restrict__ hb_u,
    const float* __restrict__ dw,
    const int* __restrict__ counts, const int* __restrict__ lists,
    const float* __restrict__ tw,
    float* __restrict__ out)
{
  __shared__ __bf16 sA[2][256 * 32];
  __shared__ __bf16 sD[2][64 * 32];
  __shared__ int    sSlot[256];

  const __bf16* hbuf = (const __bf16*)hb_u;

  // 2048 blocks = 8 XCD chunks of 256 (32 n-tiles x 8 experts)
  const int wg  = blockIdx.x;
  const int idx = wg >> 3;
  const int e   = (wg & 7) * 8 + idx / 32;
  const int n0  = (idx % 32) * 64;
  const int tid = threadIdx.x, wid = tid >> 6, lane = tid & 63;
  const int mr = wid >> 2, nc = wid & 3;
  const int n_e = counts[e];

  const int rA0 = wid * 32 + (lane >> 2);
  const int rA1 = rA0 + 16;
  const int cA  = lane & 3;
  const int aDst0 = rA0 * 64 + ((cA ^ swz(rA0)) << 4);
  const int aDst1 = rA1 * 64 + ((cA ^ swz(rA1)) << 4);

  const int cW = tid >> 3, kc = tid & 7;
  const float* dSrc = dw + ((size_t)e * HD + n0 + cW) * ID + kc * 4;
  const int wDst = cW * 64 + (((kc >> 1) ^ swz(cW)) << 4) + (kc & 1) * 8;

  const int colW  = nc * 16 + (lane & 15);
  const int wFoff = colW * 64 + (((lane >> 4) ^ swz(colW)) << 4);

#define G2_STEP(VML, BUF, A0, A1, DR, KNXT, DOI)                                  \
  {                                                                               \
    asm volatile("s_waitcnt vmcnt(" VML ")" ::: "memory");                        \
    char* bA = (char*)&sA[BUF][0];                                                \
    char* bD = (char*)&sD[BUF][0];                                                \
    *(bf16x8*)(bA + aDst0) = A0;                                                  \
    *(bf16x8*)(bA + aDst1) = A1;                                                  \
    bf16x4 dv_;                                                                   \
    _Pragma("unroll") for (int q = 0; q < 4; ++q) dv_[q] = (__bf16)DR[q];         \
    *(bf16x4*)(bD + wDst) = dv_;                                                  \
    if (DOI) {                                                                    \
      A0 = *(const bf16x8*)(aSrc0 + (KNXT));                                      \
      A1 = *(const bf16x8*)(aSrc1 + (KNXT));                                      \
      DR = *(const f32x4*)(dSrc + (KNXT));                                        \
    }                                                                             \
    LGKM0; BAR();                                                                 \
    __builtin_amdgcn_sched_barrier(0);                                            \
    bf16x8 dF_ = *(const bf16x8*)(bD + wFoff);                                    \
    _Pragma("unroll") for (int q = 0; q < 8; ++q) if (q * 16 < rows_here) {       \
      int row = mr * 128 + q * 16 + (lane & 15);                                  \
      bf16x8 aF_ = *(const bf16x8*)(bA + row * 64 + (((lane >> 4) ^ swz(row)) << 4)); \
      acc[q] = __builtin_amdgcn_mfma_f32_16x16x32_bf16(aF_, dF_, acc[q], 0, 0, 0);    \
    }                                                                             \
  }

  for (int m0 = 0; m0 < n_e; m0 += 256) {
    __syncthreads();
    if (tid < 256) sSlot[tid] = (m0 + tid < n_e) ? lists[e * T_TOK + m0 + tid] : 0;
    __syncthreads();

    const __bf16* aSrc0 = hbuf + (size_t)sSlot[rA0] * ID + cA * 8;
    const __bf16* aSrc1 = hbuf + (size_t)sSlot[rA1] * ID + cA * 8;

    f32x4 acc[8];
    const f32x4 vzero = {0.f, 0.f, 0.f, 0.f};
    #pragma unroll
    for (int q = 0; q < 8; ++q) acc[q] = vzero;

    const int rows_here = n_e - m0 - mr * 128;

    bf16x8 a0A = *(const bf16x8*)aSrc0;
    bf16x8 a1A = *(const bf16x8*)aSrc1;
    f32x4  dA  = *(const f32x4*)dSrc;
    bf16x8 a0B = *(const bf16x8*)(aSrc0 + 32);
    bf16x8 a1B = *(const bf16x8*)(aSrc1 + 32);
    f32x4  dB  = *(const f32x4*)(dSrc + 32);

    #pragma unroll 1
    for (int it = 0; it < 11; ++it) {                 // steps 0..21
      const int t = 2 * it;
      G2_STEP("3", 0, a0A, a1A, dA, (t + 2) * 32, 1)
      G2_STEP("3", 1, a0B, a1B, dB, (t + 3) * 32, 1)
    }
    G2_STEP("3", 0, a0A, a1A, dA, 0, 0)               // step 22
    G2_STEP("0", 1, a0B, a1B, dB, 0, 0)               // step 23

    #pragma unroll
    for (int q = 0; q < 8; ++q) if (q * 16 < rows_here) {
      #pragma unroll
      for (int j = 0; j < 4; ++j) {
        int row = mr * 128 + q * 16 + (lane >> 4) * 4 + j;
        if (m0 + row < n_e) {
          int s = sSlot[row];
          int token = s >> 3;
          float w = tw[s];
          atomicAdd(out + (size_t)token * HD + (size_t)(n0 + colW),
                    w * acc[q][j]);
        }
      }
    }
  }
#undef G2_STEP
}

// ---------------------------------------------------------------------------
// Launcher. ws: xb bf16 | tw | counts | lists | hidden_buf bf16 (~17 MB).
// ---------------------------------------------------------------------------
extern "C" void kernel_launch(void* const* d_in, const int* in_sizes, int n_in,
                              void* d_out, int out_size, void* d_ws, size_t ws_size,
                              hipStream_t stream) {
  const float* x  = (const float*)d_in[0];
  const float* rw = (const float*)d_in[1];
  const float* gw = (const float*)d_in[2];
  const float* uw = (const float*)d_in[3];
  const float* dw = (const float*)d_in[4];
  float* out = (float*)d_out;

  char* ws = (char*)d_ws;
  const size_t XB_OFF  = 0;
  const size_t TW_OFF  = XB_OFF + (size_t)T_TOK * HD * 2;
  const size_t CNT_OFF = TW_OFF + (size_t)T_TOK * TOPK * 4;
  const size_t LST_OFF = CNT_OFF + 256;
  const size_t HB_OFF  = LST_OFF + (size_t)NE * T_TOK * 4;

  unsigned short* xb  = (unsigned short*)(ws + XB_OFF);
  float*          tw  = (float*)(ws + TW_OFF);
  int*            cnt = (int*)(ws + CNT_OFF);
  int*            lst = (int*)(ws + LST_OFF);
  unsigned short* hb  = (unsigned short*)(ws + HB_OFF);

  hipMemsetAsync(cnt, 0, 256, stream);
  hipMemsetAsync(d_out, 0, (size_t)T_TOK * HD * sizeof(float), stream);

  router_kernel<<<T_TOK, 256, 0, stream>>>(x, rw, xb, tw, cnt, lst);
  gemm1_kernel<<<768, 512, 0, stream>>>(xb, gw, uw, cnt, lst, hb);
  gemm2_kernel<<<2048, 512, 0, stream>>>(hb, dw, cnt, lst, tw, out);
}

// Round 7
// 1160.324 us; speedup vs baseline: 34.7561x; 34.7561x over previous
//
#include <hip/hip_runtime.h>

#define T_TOK 1024
#define HD    2048
#define NE    64
#define ID    768
#define TOPK  8

typedef __bf16 bf16x8 __attribute__((ext_vector_type(8)));
typedef __bf16 bf16x4 __attribute__((ext_vector_type(4)));
typedef float  f32x4  __attribute__((ext_vector_type(4)));

#define LGKM0 asm volatile("s_waitcnt lgkmcnt(0)" ::: "memory")
#define MEMFENCE asm volatile("" ::: "memory")
#define BAR() __builtin_amdgcn_s_barrier()

// ---------------------------------------------------------------------------
// Router: fp64 logits -> top-8 -> renormalized weights; per-expert lists;
// x -> bf16.
// ---------------------------------------------------------------------------
__global__ __launch_bounds__(256) void router_kernel(
    const float* __restrict__ x, const float* __restrict__ rw,
    unsigned short* __restrict__ xb_u, float* __restrict__ tw,
    int* __restrict__ counts, int* __restrict__ lists)
{
  __shared__ float  sx[HD];
  __shared__ double slog[NE];
  const int t = blockIdx.x;
  const int tid = threadIdx.x;
  __bf16* xb = (__bf16*)xb_u;

  for (int i = tid; i < HD; i += 256) {
    float v = x[(size_t)t * HD + i];
    sx[i] = v;
    xb[(size_t)t * HD + i] = (__bf16)v;
  }
  __syncthreads();

  const int e = tid >> 2, p = tid & 3;
  const float* rwrow = rw + (size_t)e * HD;
  double acc = 0.0;
  for (int k = p; k < HD; k += 4)
    acc += (double)sx[k] * (double)rwrow[k];
  acc += __shfl_xor(acc, 1, 64);
  acc += __shfl_xor(acc, 2, 64);
  if (p == 0) slog[e] = acc;
  __syncthreads();

  if (tid < 64) {
    double v = slog[tid];
    double selv = -1e300; int seli = 0; double gmax = 0.0;
    #pragma unroll
    for (int k = 0; k < TOPK; ++k) {
      double bv = v; int bi = tid;
      #pragma unroll
      for (int off = 32; off >= 1; off >>= 1) {
        double ov = __shfl_xor(bv, off, 64);
        int    oi = __shfl_xor(bi, off, 64);
        if (ov > bv || (ov == bv && oi < bi)) { bv = ov; bi = oi; }
      }
      if (k == 0) gmax = bv;
      if (tid == k) { selv = bv; seli = bi; }
      if (tid == bi) v = -1e300;
    }
    double e_ = (tid < TOPK) ? exp(selv - gmax) : 0.0;
    double s = e_;
    #pragma unroll
    for (int off = 32; off >= 1; off >>= 1) s += __shfl_xor(s, off, 64);
    if (tid < TOPK) {
      int slot = t * TOPK + tid;
      tw[slot] = (float)(e_ / s);
      int pos = atomicAdd(&counts[seli], 1);
      lists[seli * T_TOK + pos] = slot;
    }
  }
}

// ---------------------------------------------------------------------------
// GEMM1: BM=192, BN=32 (dual gate+up), super-step SK=128 (4 sub-steps of 32).
// Weight rows read as 512-B contiguous runs (2 rows per wave-instruction).
// Single-buffered LDS; loads for t+1 in flight across both raw barriers.
// 8 waves = 4M x 2N. Grid 1536 = 8 XCD chunks (expert pinned to XCD).
// ---------------------------------------------------------------------------
__global__ __launch_bounds__(512, 4) void gemm1_kernel(
    const unsigned short* __restrict__ xb_u,
    const float* __restrict__ gw, const float* __restrict__ uw,
    const int* __restrict__ counts, const int* __restrict__ lists,
    unsigned short* __restrict__ hb_u)
{
  __shared__ __bf16 sA[192 * 128];   // 48 KB, 256-B rows, 16-chunk XOR swizzle
  __shared__ __bf16 sW[64 * 128];    // 16 KB: rows 0-31 G cols, 32-63 U cols
  __shared__ int    sSlot[192];

  const char* xbp = (const char*)xb_u;
  __bf16* hb = (__bf16*)hb_u;

  const int wg  = blockIdx.x;
  const int idx = wg >> 3;                   // 0..191
  const int e   = (wg & 7) * 8 + idx / 24;
  const int n0  = (idx % 24) * 32;           // over I=768
  const int tid = threadIdx.x, wid = tid >> 6, lane = tid & 63;
  const int mr = wid >> 1, nc = wid & 1;     // 4M x 2N
  const int n_e = counts[e];

  // A staging: 6 x bf16x8 per thread; row_j = j*32 + (tid>>4), chunk = tid&15
  const int aRowB = tid >> 4, aChk = tid & 15;
  // W staging: 4 x f32x4 per thread; row_i = i*16 + wid*2 + (lane>>5),
  // 32 lanes cover one row's 512-B contiguous fp32 run.
  const int wRowB = wid * 2 + (lane >> 5);
  const int wl = lane & 31;

  const char* gp = (const char*)gw;
  const char* up = (const char*)up;  // placeholder fixed below
  (void)up;
  const char* upp = (const char*)uw;

  unsigned wOff[4];
  #pragma unroll
  for (int i = 0; i < 4; ++i) {
    int r = i * 16 + wRowB;
    unsigned col = (unsigned)(n0 + (r & 31));
    wOff[i] = ((unsigned)e * ID + col) * (HD * 4) + (unsigned)wl * 16;
  }

  char* sAc = (char*)sA;
  char* sWc = (char*)sW;

  for (int m0 = 0; m0 < n_e; m0 += 192) {
    __syncthreads();
    if (tid < 192) sSlot[tid] = (m0 + tid < n_e) ? lists[e * T_TOK + m0 + tid] : 0;
    __syncthreads();

    unsigned aOff[6];
    #pragma unroll
    for (int j = 0; j < 6; ++j) {
      int r = j * 32 + aRowB;
      aOff[j] = (unsigned)((sSlot[r] >> 3) * (HD * 2)) + (unsigned)aChk * 16;
    }

    f32x4 accg[3], accu[3];
    const f32x4 vzero = {0.f, 0.f, 0.f, 0.f};
    #pragma unroll
    for (int q = 0; q < 3; ++q) { accg[q] = vzero; accu[q] = vzero; }

    const int rows_here = n_e - m0 - mr * 48;   // wave-uniform

    // prologue: issue loads for t=0
    bf16x8 a0 = *(const bf16x8*)(xbp + aOff[0]);
    bf16x8 a1 = *(const bf16x8*)(xbp + aOff[1]);
    bf16x8 a2 = *(const bf16x8*)(xbp + aOff[2]);
    bf16x8 a3 = *(const bf16x8*)(xbp + aOff[3]);
    bf16x8 a4 = *(const bf16x8*)(xbp + aOff[4]);
    bf16x8 a5 = *(const bf16x8*)(xbp + aOff[5]);
    f32x4  w0 = *(const f32x4*)(gp  + wOff[0]);
    f32x4  w1 = *(const f32x4*)(gp  + wOff[1]);
    f32x4  w2 = *(const f32x4*)(upp + wOff[2]);
    f32x4  w3 = *(const f32x4*)(upp + wOff[3]);
    MEMFENCE;

    #pragma unroll 1
    for (int t = 0; t < HD / 128; ++t) {          // 16 super-steps
      // ds_write tile t (compiler auto-waits the feeding loads; they arrived
      // a full super-step ago)
      #pragma unroll
      for (int j = 0; j < 6; ++j) {
        int r = j * 32 + aRowB;
        bf16x8 av = (j == 0) ? a0 : (j == 1) ? a1 : (j == 2) ? a2
                  : (j == 3) ? a3 : (j == 4) ? a4 : a5;
        *(bf16x8*)(sAc + r * 256 + ((aChk ^ (r & 15)) << 4)) = av;
      }
      #pragma unroll
      for (int i = 0; i < 4; ++i) {
        int r = i * 16 + wRowB;
        f32x4 wv = (i == 0) ? w0 : (i == 1) ? w1 : (i == 2) ? w2 : w3;
        bf16x4 wb;
        #pragma unroll
        for (int q = 0; q < 4; ++q) wb[q] = (__bf16)wv[q];
        *(bf16x4*)(sWc + r * 256 + ((((wl >> 1) ^ (r & 15))) << 4) + (wl & 1) * 8) = wb;
      }
      // issue loads for t+1 (stay in flight across barriers + compute)
      if (t < HD / 128 - 1) {
        const unsigned ka = (unsigned)(t + 1) * 256;   // bf16 bytes
        const unsigned kw = (unsigned)(t + 1) * 512;   // fp32 bytes
        a0 = *(const bf16x8*)(xbp + aOff[0] + ka);
        a1 = *(const bf16x8*)(xbp + aOff[1] + ka);
        a2 = *(const bf16x8*)(xbp + aOff[2] + ka);
        a3 = *(const bf16x8*)(xbp + aOff[3] + ka);
        a4 = *(const bf16x8*)(xbp + aOff[4] + ka);
        a5 = *(const bf16x8*)(xbp + aOff[5] + ka);
        w0 = *(const f32x4*)(gp  + wOff[0] + kw);
        w1 = *(const f32x4*)(gp  + wOff[1] + kw);
        w2 = *(const f32x4*)(upp + wOff[2] + kw);
        w3 = *(const f32x4*)(upp + wOff[3] + kw);
      }
      MEMFENCE;
      LGKM0; BAR(); MEMFENCE;

      #pragma unroll
      for (int ss = 0; ss < 4; ++ss) {
        const int chk = ss * 4 + (lane >> 4);
        const int wrow = nc * 16 + (lane & 15);
        bf16x8 gF = *(const bf16x8*)(sWc + wrow * 256 + ((chk ^ (wrow & 15)) << 4));
        bf16x8 uF = *(const bf16x8*)(sWc + (wrow + 32) * 256 + ((chk ^ (wrow & 15)) << 4));
        bf16x8 aF0, aF1, aF2;
        {
          int r0 = mr * 48 + (lane & 15);
          int r1 = r0 + 16, r2 = r0 + 32;
          aF0 = *(const bf16x8*)(sAc + r0 * 256 + ((chk ^ (r0 & 15)) << 4));
          aF1 = *(const bf16x8*)(sAc + r1 * 256 + ((chk ^ (r1 & 15)) << 4));
          aF2 = *(const bf16x8*)(sAc + r2 * 256 + ((chk ^ (r2 & 15)) << 4));
        }
        if (0 < rows_here) {
          accg[0] = __builtin_amdgcn_mfma_f32_16x16x32_bf16(aF0, gF, accg[0], 0, 0, 0);
          accu[0] = __builtin_amdgcn_mfma_f32_16x16x32_bf16(aF0, uF, accu[0], 0, 0, 0);
        }
        if (16 < rows_here) {
          accg[1] = __builtin_amdgcn_mfma_f32_16x16x32_bf16(aF1, gF, accg[1], 0, 0, 0);
          accu[1] = __builtin_amdgcn_mfma_f32_16x16x32_bf16(aF1, uF, accu[1], 0, 0, 0);
        }
        if (32 < rows_here) {
          accg[2] = __builtin_amdgcn_mfma_f32_16x16x32_bf16(aF2, gF, accg[2], 0, 0, 0);
          accu[2] = __builtin_amdgcn_mfma_f32_16x16x32_bf16(aF2, uF, accu[2], 0, 0, 0);
        }
      }
      BAR(); MEMFENCE;
    }

    // epilogue: silu(g)*u -> bf16 hidden_buf
    #pragma unroll
    for (int q = 0; q < 3; ++q) if (q * 16 < rows_here) {
      #pragma unroll
      for (int j = 0; j < 4; ++j) {
        int row = mr * 48 + q * 16 + (lane >> 4) * 4 + j;
        if (m0 + row < n_e) {
          int s = sSlot[row];
          float g = accg[q][j], u = accu[q][j];
          float h = (g / (1.0f + expf(-g))) * u;
          hb[(size_t)s * ID + (size_t)(n0 + nc * 16 + (lane & 15))] = (__bf16)h;
        }
      }
    }
  }
}

// ---------------------------------------------------------------------------
// GEMM2: BM=192, BN=64 H-cols, K=768 (6 super-steps of 128). Same structure.
// 8 waves = 2M x 4N. Weighted atomic scatter to out. Grid 2048.
// ---------------------------------------------------------------------------
__global__ __launch_bounds__(512, 4) void gemm2_kernel(
    const unsigned short* __restrict__ hb_u,
    const float* __restrict__ dw,
    const int* __restrict__ counts, const int* __restrict__ lists,
    const float* __restrict__ tw,
    float* __restrict__ out)
{
  __shared__ __bf16 sA[192 * 128];
  __shared__ __bf16 sW[64 * 128];
  __shared__ int    sSlot[192];

  const char* hbp = (const char*)hb_u;
  const char* dp  = (const char*)dw;

  const int wg  = blockIdx.x;
  const int idx = wg >> 3;                   // 0..255
  const int e   = (wg & 7) * 8 + idx / 32;
  const int n0  = (idx % 32) * 64;           // over H=2048
  const int tid = threadIdx.x, wid = tid >> 6, lane = tid & 63;
  const int mr = wid >> 2, nc = wid & 3;     // 2M x 4N
  const int n_e = counts[e];

  const int aRowB = tid >> 4, aChk = tid & 15;
  const int wRowB = wid * 2 + (lane >> 5);
  const int wl = lane & 31;

  unsigned wOff[4];
  #pragma unroll
  for (int i = 0; i < 4; ++i) {
    int r = i * 16 + wRowB;
    wOff[i] = ((unsigned)e * HD + (unsigned)(n0 + r)) * (ID * 4) + (unsigned)wl * 16;
  }

  char* sAc = (char*)sA;
  char* sWc = (char*)sW;

  for (int m0 = 0; m0 < n_e; m0 += 192) {
    __syncthreads();
    if (tid < 192) sSlot[tid] = (m0 + tid < n_e) ? lists[e * T_TOK + m0 + tid] : 0;
    __syncthreads();

    unsigned aOff[6];
    #pragma unroll
    for (int j = 0; j < 6; ++j) {
      int r = j * 32 + aRowB;
      aOff[j] = (unsigned)(sSlot[r] * (ID * 2)) + (unsigned)aChk * 16;
    }

    f32x4 acc[6];
    const f32x4 vzero = {0.f, 0.f, 0.f, 0.f};
    #pragma unroll
    for (int q = 0; q < 6; ++q) acc[q] = vzero;

    const int rows_here = n_e - m0 - mr * 96;

    bf16x8 a0 = *(const bf16x8*)(hbp + aOff[0]);
    bf16x8 a1 = *(const bf16x8*)(hbp + aOff[1]);
    bf16x8 a2 = *(const bf16x8*)(hbp + aOff[2]);
    bf16x8 a3 = *(const bf16x8*)(hbp + aOff[3]);
    bf16x8 a4 = *(const bf16x8*)(hbp + aOff[4]);
    bf16x8 a5 = *(const bf16x8*)(hbp + aOff[5]);
    f32x4  w0 = *(const f32x4*)(dp + wOff[0]);
    f32x4  w1 = *(const f32x4*)(dp + wOff[1]);
    f32x4  w2 = *(const f32x4*)(dp + wOff[2]);
    f32x4  w3 = *(const f32x4*)(dp + wOff[3]);
    MEMFENCE;

    #pragma unroll 1
    for (int t = 0; t < ID / 128; ++t) {          // 6 super-steps
      #pragma unroll
      for (int j = 0; j < 6; ++j) {
        int r = j * 32 + aRowB;
        bf16x8 av = (j == 0) ? a0 : (j == 1) ? a1 : (j == 2) ? a2
                  : (j == 3) ? a3 : (j == 4) ? a4 : a5;
        *(bf16x8*)(sAc + r * 256 + ((aChk ^ (r & 15)) << 4)) = av;
      }
      #pragma unroll
      for (int i = 0; i < 4; ++i) {
        int r = i * 16 + wRowB;
        f32x4 wv = (i == 0) ? w0 : (i == 1) ? w1 : (i == 2) ? w2 : w3;
        bf16x4 wb;
        #pragma unroll
        for (int q = 0; q < 4; ++q) wb[q] = (__bf16)wv[q];
        *(bf16x4*)(sWc + r * 256 + ((((wl >> 1) ^ (r & 15))) << 4) + (wl & 1) * 8) = wb;
      }
      if (t < ID / 128 - 1) {
        const unsigned ka = (unsigned)(t + 1) * 256;
        const unsigned kw = (unsigned)(t + 1) * 512;
        a0 = *(const bf16x8*)(hbp + aOff[0] + ka);
        a1 = *(const bf16x8*)(hbp + aOff[1] + ka);
        a2 = *(const bf16x8*)(hbp + aOff[2] + ka);
        a3 = *(const bf16x8*)(hbp + aOff[3] + ka);
        a4 = *(const bf16x8*)(hbp + aOff[4] + ka);
        a5 = *(const bf16x8*)(hbp + aOff[5] + ka);
        w0 = *(const f32x4*)(dp + wOff[0] + kw);
        w1 = *(const f32x4*)(dp + wOff[1] + kw);
        w2 = *(const f32x4*)(dp + wOff[2] + kw);
        w3 = *(const f32x4*)(dp + wOff[3] + kw);
      }
      MEMFENCE;
      LGKM0; BAR(); MEMFENCE;

      #pragma unroll
      for (int ss = 0; ss < 4; ++ss) {
        const int chk = ss * 4 + (lane >> 4);
        const int wrow = nc * 16 + (lane & 15);
        bf16x8 dF = *(const bf16x8*)(sWc + wrow * 256 + ((chk ^ (wrow & 15)) << 4));
        #pragma unroll
        for (int q = 0; q < 6; ++q) {
          int r = mr * 96 + q * 16 + (lane & 15);
          bf16x8 aF = *(const bf16x8*)(sAc + r * 256 + ((chk ^ (r & 15)) << 4));
          if (q * 16 < rows_here)
            acc[q] = __builtin_amdgcn_mfma_f32_16x16x32_bf16(aF, dF, acc[q], 0, 0, 0);
        }
      }
      BAR(); MEMFENCE;
    }

    #pragma unroll
    for (int q = 0; q < 6; ++q) if (q * 16 < rows_here) {
      #pragma unroll
      for (int j = 0; j < 4; ++j) {
        int row = mr * 96 + q * 16 + (lane >> 4) * 4 + j;
        if (m0 + row < n_e) {
          int s = sSlot[row];
          int token = s >> 3;
          float w = tw[s];
          atomicAdd(out + (size_t)token * HD + (size_t)(n0 + nc * 16 + (lane & 15)),
                    w * acc[q][j]);
        }
      }
    }
  }
}

// ---------------------------------------------------------------------------
// Launcher. ws: xb bf16 | tw | counts | lists | hidden_buf bf16 (~17 MB).
// ---------------------------------------------------------------------------
extern "C" void kernel_launch(void* const* d_in, const int* in_sizes, int n_in,
                              void* d_out, int out_size, void* d_ws, size_t ws_size,
                              hipStream_t stream) {
  const float* x  = (const float*)d_in[0];
  const float* rw = (const float*)d_in[1];
  const float* gw = (const float*)d_in[2];
  const float* uw = (const float*)d_in[3];
  const float* dw = (const float*)d_in[4];
  float* out = (float*)d_out;

  char* ws = (char*)d_ws;
  const size_t XB_OFF  = 0;
  const size_t TW_OFF  = XB_OFF + (size_t)T_TOK * HD * 2;
  const size_t CNT_OFF = TW_OFF + (size_t)T_TOK * TOPK * 4;
  const size_t LST_OFF = CNT_OFF + 256;
  const size_t HB_OFF  = LST_OFF + (size_t)NE * T_TOK * 4;

  unsigned short* xb  = (unsigned short*)(ws + XB_OFF);
  float*          tw  = (float*)(ws + TW_OFF);
  int*            cnt = (int*)(ws + CNT_OFF);
  int*            lst = (int*)(ws + LST_OFF);
  unsigned short* hb  = (unsigned short*)(ws + HB_OFF);

  hipMemsetAsync(cnt, 0, 256, stream);
  hipMemsetAsync(d_out, 0, (size_t)T_TOK * HD * sizeof(float), stream);

  router_kernel<<<T_TOK, 256, 0, stream>>>(x, rw, xb, tw, cnt, lst);
  gemm1_kernel<<<1536, 512, 0, stream>>>(xb, gw, uw, cnt, lst, hb);
  gemm2_kernel<<<2048, 512, 0, stream>>>(hb, dw, cnt, lst, tw, out);
}

// Round 8
// 771.875 us; speedup vs baseline: 52.2472x; 1.5033x over previous
//
#include <hip/hip_runtime.h>

#define T_TOK 1024
#define HD    2048
#define NE    64
#define ID    768
#define TOPK  8

typedef __bf16 bf16x8 __attribute__((ext_vector_type(8)));
typedef __bf16 bf16x4 __attribute__((ext_vector_type(4)));
typedef float  f32x4  __attribute__((ext_vector_type(4)));

#define LGKM0  asm volatile("s_waitcnt lgkmcnt(0)" ::: "memory")
#define VMC(N) asm volatile("s_waitcnt vmcnt(" N ")" ::: "memory")
#define BAR()  __builtin_amdgcn_s_barrier()
#define SCHED0 __builtin_amdgcn_sched_barrier(0)

// ---------------------------------------------------------------------------
// Router: fp64 logits -> top-8 -> renormalized weights; per-expert lists;
// x -> bf16.
// ---------------------------------------------------------------------------
__global__ __launch_bounds__(256) void router_kernel(
    const float* __restrict__ x, const float* __restrict__ rw,
    unsigned short* __restrict__ xb_u, float* __restrict__ tw,
    int* __restrict__ counts, int* __restrict__ lists)
{
  __shared__ float  sx[HD];
  __shared__ double slog[NE];
  const int t = blockIdx.x;
  const int tid = threadIdx.x;
  __bf16* xb = (__bf16*)xb_u;

  for (int i = tid; i < HD; i += 256) {
    float v = x[(size_t)t * HD + i];
    sx[i] = v;
    xb[(size_t)t * HD + i] = (__bf16)v;
  }
  __syncthreads();

  const int e = tid >> 2, p = tid & 3;
  const float* rwrow = rw + (size_t)e * HD;
  double acc = 0.0;
  for (int k = p; k < HD; k += 4)
    acc += (double)sx[k] * (double)rwrow[k];
  acc += __shfl_xor(acc, 1, 64);
  acc += __shfl_xor(acc, 2, 64);
  if (p == 0) slog[e] = acc;
  __syncthreads();

  if (tid < 64) {
    double v = slog[tid];
    double selv = -1e300; int seli = 0; double gmax = 0.0;
    #pragma unroll
    for (int k = 0; k < TOPK; ++k) {
      double bv = v; int bi = tid;
      #pragma unroll
      for (int off = 32; off >= 1; off >>= 1) {
        double ov = __shfl_xor(bv, off, 64);
        int    oi = __shfl_xor(bi, off, 64);
        if (ov > bv || (ov == bv && oi < bi)) { bv = ov; bi = oi; }
      }
      if (k == 0) gmax = bv;
      if (tid == k) { selv = bv; seli = bi; }
      if (tid == bi) v = -1e300;
    }
    double e_ = (tid < TOPK) ? exp(selv - gmax) : 0.0;
    double s = e_;
    #pragma unroll
    for (int off = 32; off >= 1; off >>= 1) s += __shfl_xor(s, off, 64);
    if (tid < TOPK) {
      int slot = t * TOPK + tid;
      tw[slot] = (float)(e_ / s);
      int pos = atomicAdd(&counts[seli], 1);
      lists[seli * T_TOK + pos] = slot;
    }
  }
}

// ---------------------------------------------------------------------------
// GEMM1: BM=256 tokens, BN=8 i-cols. W tile = 8 gate + 8 up rows, FULL K in
// LDS bf16 (64 KB), burst-loaded once per block as per-wave-contiguous 1-KB
// ops (8-deep rolling window). K-loop touches only A (LLC-resident) via
// 4-generation reg rotation + exact counted vmcnt. One MFMA N-frag carries
// gate (cols 0-7) and up (cols 8-15); epilogue pairs them via shfl_xor(8).
// LDS = 64K (W) + 16K (A) = 80 KB -> 2 blocks/CU.
// ---------------------------------------------------------------------------
__global__ __launch_bounds__(512, 4) void gemm1_kernel(
    const unsigned short* __restrict__ xb_u,
    const float* __restrict__ gw, const float* __restrict__ uw,
    const int* __restrict__ counts, const int* __restrict__ lists,
    unsigned short* __restrict__ hb_u)
{
  __shared__ __bf16 sW[HD / 8 * 16 * 8];   // [kg=256][row=16][k&7] = 64 KB
  __shared__ __bf16 sA[256 * 32];          // [row=256][32k], 64-B rows, 16 KB

  const char* xbp = (const char*)xb_u;
  __bf16* hb = (__bf16*)hb_u;
  char* sWc = (char*)sW;
  char* sAc = (char*)sA;

  // 6144 blocks = 8 XCD chunks of 768 (96 n-tiles x 8 experts)
  const int wg  = blockIdx.x;
  const int idx = wg >> 3;                   // 0..767
  const int e   = (wg & 7) * 8 + idx / 96;
  const int n0  = (idx % 96) * 8;            // over I=768
  const int tid = threadIdx.x, wid = tid >> 6, lane = tid & 63;
  const int n_e = counts[e];

  // ---- W burst: threads 0-255 gate, 256-511 up; 16 x 16B loads per thread.
  const int h = tid & 255;
  const int isup = tid >> 8;
  const unsigned Fb = ((unsigned)(h >> 6) << 14) + ((unsigned)(h & 63) << 4);
  const char* wsrcb = (const char*)(isup ? uw : gw)
                    + ((size_t)e * ID + n0) * (HD * 4);
  {
    f32x4 wr0, wr1, wr2, wr3, wr4, wr5, wr6, wr7;
#define WLD(R, C) R = *(const f32x4*)(wsrcb + (Fb + (C) * 1024u))
#define WST(R, C) { \
      unsigned F_ = Fb + (C) * 1024u; \
      unsigned row_ = (F_ >> 13) + (unsigned)isup * 8u; \
      unsigned k4_ = (F_ >> 2) & 2047u; \
      bf16x4 b_; \
      _Pragma("unroll") for (int q = 0; q < 4; ++q) b_[q] = (__bf16)R[q]; \
      *(bf16x4*)(sWc + ((k4_ >> 3) * 256u + row_ * 16u + (k4_ & 7u) * 2u)) = b_; }
    WLD(wr0, 0); WLD(wr1, 1); WLD(wr2, 2); WLD(wr3, 3);
    WLD(wr4, 4); WLD(wr5, 5); WLD(wr6, 6); WLD(wr7, 7);
    VMC("4"); WST(wr0, 0) WST(wr1, 1) WST(wr2, 2) WST(wr3, 3)
    WLD(wr0, 8); WLD(wr1, 9); WLD(wr2, 10); WLD(wr3, 11);
    VMC("4"); WST(wr4, 4) WST(wr5, 5) WST(wr6, 6) WST(wr7, 7)
    WLD(wr4, 12); WLD(wr5, 13); WLD(wr6, 14); WLD(wr7, 15);
    VMC("4"); WST(wr0, 8) WST(wr1, 9) WST(wr2, 10) WST(wr3, 11)
    VMC("0"); WST(wr4, 12) WST(wr5, 13) WST(wr6, 14) WST(wr7, 15)
#undef WLD
#undef WST
  }
  LGKM0; BAR();   // W resident for the whole block lifetime

  // A staging geometry: thread covers row r=tid>>1, 32 B half s=tid&1
  const int rS = tid >> 1, sS = tid & 1;
  const int aDst0 = rS * 64 + (((2 * sS) ^ (rS & 3)) << 4);
  const int aDst1 = rS * 64 + (((2 * sS + 1) ^ (rS & 3)) << 4);

  // frag geometry (constant per thread; single-buffered sA)
  const int f0 = 2 * wid, f1 = 2 * wid + 1;
  const int rowF0 = f0 * 16 + (lane & 15), rowF1 = f1 * 16 + (lane & 15);
  const int cF = lane >> 4;
  const int afb0 = rowF0 * 64 + ((cF ^ (rowF0 & 3)) << 4);
  const int afb1 = rowF1 * 64 + ((cF ^ (rowF1 & 3)) << 4);
  const unsigned wfb0 = (unsigned)(lane >> 4) * 256u + (unsigned)(lane & 15) * 16u;

#define STEP1(VML, A0, A1, DOI)                                        \
  { VMC(VML);                                                          \
    *(bf16x8*)(sAc + aDst0) = A0;                                      \
    *(bf16x8*)(sAc + aDst1) = A1;                                      \
    if (DOI) { A0 = *(const bf16x8*)(aNext);                           \
               A1 = *(const bf16x8*)(aNext + 16); aNext += 64; }       \
    LGKM0; BAR(); SCHED0;                                              \
    bf16x8 wF = *(const bf16x8*)(sWc + wfb); wfb += 1024u;             \
    bf16x8 aF0 = *(const bf16x8*)(sAc + afb0);                         \
    bf16x8 aF1 = *(const bf16x8*)(sAc + afb1);                         \
    if (ok0) acc0 = __builtin_amdgcn_mfma_f32_16x16x32_bf16(aF0, wF, acc0, 0, 0, 0); \
    if (ok1) acc1 = __builtin_amdgcn_mfma_f32_16x16x32_bf16(aF1, wF, acc1, 0, 0, 0); \
    BAR(); }

  for (int m0 = 0; m0 < n_e; m0 += 256) {
    VMC("0");   // drain prior-pass epilogue stores (keeps counting exact)
    const int rem = n_e - m0;
    const int sl = (m0 + rS < n_e) ? lists[e * T_TOK + m0 + rS] : 0;
    const char* aSrc = xbp + (size_t)(sl >> 3) * (HD * 2) + sS * 32;
    const bool ok0 = (f0 * 16 < rem), ok1 = (f1 * 16 < rem);

    f32x4 acc0 = {0.f, 0.f, 0.f, 0.f}, acc1 = {0.f, 0.f, 0.f, 0.f};

    bf16x8 a00 = *(const bf16x8*)(aSrc);       bf16x8 a01 = *(const bf16x8*)(aSrc + 16);
    bf16x8 a10 = *(const bf16x8*)(aSrc + 64);  bf16x8 a11 = *(const bf16x8*)(aSrc + 80);
    bf16x8 a20 = *(const bf16x8*)(aSrc + 128); bf16x8 a21 = *(const bf16x8*)(aSrc + 144);
    bf16x8 a30 = *(const bf16x8*)(aSrc + 192); bf16x8 a31 = *(const bf16x8*)(aSrc + 208);
    const char* aNext = aSrc + 256;
    unsigned wfb = wfb0;

    #pragma unroll 1
    for (int it = 0; it < 15; ++it) {          // steps 0..59
      STEP1("6", a00, a01, 1)
      STEP1("6", a10, a11, 1)
      STEP1("6", a20, a21, 1)
      STEP1("6", a30, a31, 1)
    }
    STEP1("6", a00, a01, 0)                    // step 60
    STEP1("4", a10, a11, 0)                    // step 61
    STEP1("2", a20, a21, 0)                    // step 62
    STEP1("0", a30, a31, 0)                    // step 63

    // epilogue: col(lane&15): 0-7 gate / 8-15 up; pair via shfl_xor(8)
    #pragma unroll
    for (int fi = 0; fi < 2; ++fi) {
      const int f = (fi == 0) ? f0 : f1;
      #pragma unroll
      for (int j = 0; j < 4; ++j) {
        int row = f * 16 + (lane >> 4) * 4 + j;
        if (row < rem) {
          float gv = (fi == 0) ? acc0[j] : acc1[j];
          float uv = __shfl_xor(gv, 8, 64);
          if ((lane & 8) == 0) {
            int s = lists[e * T_TOK + m0 + row];
            float hv = (gv / (1.0f + expf(-gv))) * uv;
            hb[(size_t)s * ID + (size_t)(n0 + (lane & 7))] = (__bf16)hv;
          }
        }
      }
    }
  }
#undef STEP1
}

// ---------------------------------------------------------------------------
// GEMM2: BM=256, BN=16 H-cols. W tile = 16 rows x full K=768 in LDS bf16
// (24 KB), burst-loaded once (6 x 16B per thread). Same A pipeline (K=768,
// 24 steps). Weighted atomic scatter. LDS = 40 KB -> 2 blocks/CU.
// ---------------------------------------------------------------------------
__global__ __launch_bounds__(512, 4) void gemm2_kernel(
    const unsigned short* __restrict__ hb_u,
    const float* __restrict__ dw,
    const int* __restrict__ counts, const int* __restrict__ lists,
    const float* __restrict__ tw,
    float* __restrict__ out)
{
  __shared__ __bf16 sW[ID / 8 * 16 * 8];   // [kg=96][row=16][k&7] = 24 KB
  __shared__ __bf16 sA[256 * 32];          // 16 KB

  const char* hbp = (const char*)hb_u;
  char* sWc = (char*)sW;
  char* sAc = (char*)sA;

  // 8192 blocks = 8 XCD chunks of 1024 (128 n-tiles x 8 experts)
  const int wg  = blockIdx.x;
  const int idx = wg >> 3;                   // 0..1023
  const int e   = (wg & 7) * 8 + idx / 128;
  const int n0  = (idx % 128) * 16;          // over H=2048
  const int tid = threadIdx.x, wid = tid >> 6, lane = tid & 63;
  const int n_e = counts[e];

  // ---- W burst: 48 KB fp32, 6 x 16B per thread, per-wave-contiguous 1 KB.
  const unsigned Fb = (unsigned)wid * 6144u + (unsigned)lane * 16u;
  const char* wsrcb = (const char*)dw + ((size_t)e * HD + n0) * (ID * 4);
  {
    f32x4 wr0, wr1, wr2, wr3, wr4, wr5;
#define WLD(R, C) R = *(const f32x4*)(wsrcb + (Fb + (C) * 1024u))
#define WST(R, C) { \
      unsigned F_ = Fb + (C) * 1024u; \
      unsigned row_ = F_ / 3072u; \
      unsigned k4_ = (F_ - row_ * 3072u) >> 2; \
      bf16x4 b_; \
      _Pragma("unroll") for (int q = 0; q < 4; ++q) b_[q] = (__bf16)R[q]; \
      *(bf16x4*)(sWc + ((k4_ >> 3) * 256u + row_ * 16u + (k4_ & 7u) * 2u)) = b_; }
    WLD(wr0, 0); WLD(wr1, 1); WLD(wr2, 2); WLD(wr3, 3); WLD(wr4, 4); WLD(wr5, 5);
    VMC("2"); WST(wr0, 0) WST(wr1, 1) WST(wr2, 2) WST(wr3, 3)
    VMC("0"); WST(wr4, 4) WST(wr5, 5)
#undef WLD
#undef WST
  }
  LGKM0; BAR();

  const int rS = tid >> 1, sS = tid & 1;
  const int aDst0 = rS * 64 + (((2 * sS) ^ (rS & 3)) << 4);
  const int aDst1 = rS * 64 + (((2 * sS + 1) ^ (rS & 3)) << 4);

  const int f0 = 2 * wid, f1 = 2 * wid + 1;
  const int rowF0 = f0 * 16 + (lane & 15), rowF1 = f1 * 16 + (lane & 15);
  const int cF = lane >> 4;
  const int afb0 = rowF0 * 64 + ((cF ^ (rowF0 & 3)) << 4);
  const int afb1 = rowF1 * 64 + ((cF ^ (rowF1 & 3)) << 4);
  const unsigned wfb0 = (unsigned)(lane >> 4) * 256u + (unsigned)(lane & 15) * 16u;

#define STEP2(VML, A0, A1, DOI)                                        \
  { VMC(VML);                                                          \
    *(bf16x8*)(sAc + aDst0) = A0;                                      \
    *(bf16x8*)(sAc + aDst1) = A1;                                      \
    if (DOI) { A0 = *(const bf16x8*)(aNext);                           \
               A1 = *(const bf16x8*)(aNext + 16); aNext += 64; }       \
    LGKM0; BAR(); SCHED0;                                              \
    bf16x8 wF = *(const bf16x8*)(sWc + wfb); wfb += 1024u;             \
    bf16x8 aF0 = *(const bf16x8*)(sAc + afb0);                         \
    bf16x8 aF1 = *(const bf16x8*)(sAc + afb1);                         \
    if (ok0) acc0 = __builtin_amdgcn_mfma_f32_16x16x32_bf16(aF0, wF, acc0, 0, 0, 0); \
    if (ok1) acc1 = __builtin_amdgcn_mfma_f32_16x16x32_bf16(aF1, wF, acc1, 0, 0, 0); \
    BAR(); }

  for (int m0 = 0; m0 < n_e; m0 += 256) {
    VMC("0");
    const int rem = n_e - m0;
    const int sl = (m0 + rS < n_e) ? lists[e * T_TOK + m0 + rS] : 0;
    const char* aSrc = hbp + (size_t)sl * (ID * 2) + sS * 32;
    const bool ok0 = (f0 * 16 < rem), ok1 = (f1 * 16 < rem);

    f32x4 acc0 = {0.f, 0.f, 0.f, 0.f}, acc1 = {0.f, 0.f, 0.f, 0.f};

    bf16x8 a00 = *(const bf16x8*)(aSrc);       bf16x8 a01 = *(const bf16x8*)(aSrc + 16);
    bf16x8 a10 = *(const bf16x8*)(aSrc + 64);  bf16x8 a11 = *(const bf16x8*)(aSrc + 80);
    bf16x8 a20 = *(const bf16x8*)(aSrc + 128); bf16x8 a21 = *(const bf16x8*)(aSrc + 144);
    bf16x8 a30 = *(const bf16x8*)(aSrc + 192); bf16x8 a31 = *(const bf16x8*)(aSrc + 208);
    const char* aNext = aSrc + 256;
    unsigned wfb = wfb0;

    #pragma unroll 1
    for (int it = 0; it < 5; ++it) {           // steps 0..19
      STEP2("6", a00, a01, 1)
      STEP2("6", a10, a11, 1)
      STEP2("6", a20, a21, 1)
      STEP2("6", a30, a31, 1)
    }
    STEP2("6", a00, a01, 0)                    // step 20
    STEP2("4", a10, a11, 0)                    // step 21
    STEP2("2", a20, a21, 0)                    // step 22
    STEP2("0", a30, a31, 0)                    // step 23

    #pragma unroll
    for (int fi = 0; fi < 2; ++fi) {
      const int f = (fi == 0) ? f0 : f1;
      #pragma unroll
      for (int j = 0; j < 4; ++j) {
        int row = f * 16 + (lane >> 4) * 4 + j;
        if (row < rem) {
          int s = lists[e * T_TOK + m0 + row];
          float w = tw[s];
          float v = (fi == 0) ? acc0[j] : acc1[j];
          atomicAdd(out + (size_t)(s >> 3) * HD + (size_t)(n0 + (lane & 15)),
                    w * v);
        }
      }
    }
  }
#undef STEP2
}

// ---------------------------------------------------------------------------
// Launcher. ws: xb bf16 | tw | counts | lists | hidden_buf bf16 (~17 MB).
// ---------------------------------------------------------------------------
extern "C" void kernel_launch(void* const* d_in, const int* in_sizes, int n_in,
                              void* d_out, int out_size, void* d_ws, size_t ws_size,
                              hipStream_t stream) {
  const float* x  = (const float*)d_in[0];
  const float* rw = (const float*)d_in[1];
  const float* gw = (const float*)d_in[2];
  const float* uw = (const float*)d_in[3];
  const float* dw = (const float*)d_in[4];
  float* out = (float*)d_out;

  char* ws = (char*)d_ws;
  const size_t XB_OFF  = 0;
  const size_t TW_OFF  = XB_OFF + (size_t)T_TOK * HD * 2;
  const size_t CNT_OFF = TW_OFF + (size_t)T_TOK * TOPK * 4;
  const size_t LST_OFF = CNT_OFF + 256;
  const size_t HB_OFF  = LST_OFF + (size_t)NE * T_TOK * 4;

  unsigned short* xb  = (unsigned short*)(ws + XB_OFF);
  float*          tw  = (float*)(ws + TW_OFF);
  int*            cnt = (int*)(ws + CNT_OFF);
  int*            lst = (int*)(ws + LST_OFF);
  unsigned short* hb  = (unsigned short*)(ws + HB_OFF);

  hipMemsetAsync(cnt, 0, 256, stream);
  hipMemsetAsync(d_out, 0, (size_t)T_TOK * HD * sizeof(float), stream);

  router_kernel<<<T_TOK, 256, 0, stream>>>(x, rw, xb, tw, cnt, lst);
  gemm1_kernel<<<6144, 512, 0, stream>>>(xb, gw, uw, cnt, lst, hb);
  gemm2_kernel<<<8192, 512, 0, stream>>>(hb, dw, cnt, lst, tw, out);
}

// Round 9
// 516.855 us; speedup vs baseline: 78.0263x; 1.4934x over previous
//
#include <hip/hip_runtime.h>

#define T_TOK 1024
#define HD    2048
#define NE    64
#define ID    768
#define TOPK  8

typedef __bf16 bf16x8 __attribute__((ext_vector_type(8)));
typedef float  f32x4  __attribute__((ext_vector_type(4)));

#define LGKM0  asm volatile("s_waitcnt lgkmcnt(0)" ::: "memory")
#define VMC(N) asm volatile("s_waitcnt vmcnt(" N ")" ::: "memory")
#define BAR()  __builtin_amdgcn_s_barrier()
#define SCHED0 __builtin_amdgcn_sched_barrier(0)
#define FENCE  asm volatile("" ::: "memory")

__device__ __forceinline__ void load_lds16(const void* src, void* lds) {
  __builtin_amdgcn_global_load_lds(
      (const __attribute__((address_space(1))) void*)src,
      (__attribute__((address_space(3))) void*)lds, 16, 0, 0);
}

__device__ __forceinline__ bf16x8 cvt8(f32x4 a, f32x4 b) {
  bf16x8 r;
  #pragma unroll
  for (int j = 0; j < 4; ++j) { r[j] = (__bf16)a[j]; r[j + 4] = (__bf16)b[j]; }
  return r;
}

// ---------------------------------------------------------------------------
// Router: fp64 logits -> top-8 -> renormalized weights; per-expert lists;
// x -> bf16.
// ---------------------------------------------------------------------------
__global__ __launch_bounds__(256) void router_kernel(
    const float* __restrict__ x, const float* __restrict__ rw,
    unsigned short* __restrict__ xb_u, float* __restrict__ tw,
    int* __restrict__ counts, int* __restrict__ lists)
{
  __shared__ float  sx[HD];
  __shared__ double slog[NE];
  const int t = blockIdx.x;
  const int tid = threadIdx.x;
  __bf16* xb = (__bf16*)xb_u;

  for (int i = tid; i < HD; i += 256) {
    float v = x[(size_t)t * HD + i];
    sx[i] = v;
    xb[(size_t)t * HD + i] = (__bf16)v;
  }
  __syncthreads();

  const int e = tid >> 2, p = tid & 3;
  const float* rwrow = rw + (size_t)e * HD;
  double acc = 0.0;
  for (int k = p; k < HD; k += 4)
    acc += (double)sx[k] * (double)rwrow[k];
  acc += __shfl_xor(acc, 1, 64);
  acc += __shfl_xor(acc, 2, 64);
  if (p == 0) slog[e] = acc;
  __syncthreads();

  if (tid < 64) {
    double v = slog[tid];
    double selv = -1e300; int seli = 0; double gmax = 0.0;
    #pragma unroll
    for (int k = 0; k < TOPK; ++k) {
      double bv = v; int bi = tid;
      #pragma unroll
      for (int off = 32; off >= 1; off >>= 1) {
        double ov = __shfl_xor(bv, off, 64);
        int    oi = __shfl_xor(bi, off, 64);
        if (ov > bv || (ov == bv && oi < bi)) { bv = ov; bi = oi; }
      }
      if (k == 0) gmax = bv;
      if (tid == k) { selv = bv; seli = bi; }
      if (tid == bi) v = -1e300;
    }
    double e_ = (tid < TOPK) ? exp(selv - gmax) : 0.0;
    double s = e_;
    #pragma unroll
    for (int off = 32; off >= 1; off >>= 1) s += __shfl_xor(s, off, 64);
    if (tid < TOPK) {
      int slot = t * TOPK + tid;
      tw[slot] = (float)(e_ / s);
      int pos = atomicAdd(&counts[seli], 1);
      lists[seli * T_TOK + pos] = slot;
    }
  }
}

// ---------------------------------------------------------------------------
// GEMM1: block = (expert, 64 i-cols). M=192 tokens, BK=128, 16 K-steps.
// A double-buffered in LDS (2 x 48 KB) via global_load_lds, one barrier/step.
// Each wave streams its 16 W-rows (waves 0-3 gate, 4-7 up) straight to
// MFMA B-frag registers: per step 8 x f32x4 giving 512 B/row of CONCURRENT
// demand, sequential across steps (DRAM page friendly). Counted vmcnt(8)
// drains only A before each barrier; W never drained.
// ---------------------------------------------------------------------------
__global__ __launch_bounds__(512, 2) void gemm1_kernel(
    const unsigned short* __restrict__ xb_u,
    const float* __restrict__ gw, const float* __restrict__ uw,
    const int* __restrict__ counts, const int* __restrict__ lists,
    unsigned short* __restrict__ hb_u)
{
  __shared__ __bf16 sA[2][24576];   // 2 x 192 x 128 bf16 = 2 x 48 KB
  __shared__ int    sSlot[192];

  const char* xbp = (const char*)xb_u;
  __bf16* hb = (__bf16*)hb_u;
  char* sAc = (char*)&sA[0][0];

  // 768 blocks = 8 XCD chunks of 96 (12 n-tiles x 8 experts)
  const int wg  = blockIdx.x;
  const int idx = wg >> 3;
  const int e   = (wg & 7) * 8 + idx / 12;
  const int n0  = (idx % 12) * 64;
  const int tid = threadIdx.x, wid = tid >> 6, lane = tid & 63;
  const int n_e = counts[e];
  const int isu = wid >> 2;

  // per-lane W byte address: row = n0 + (wid&3)*16 + (lane&15); +32B per k-quarter
  const char* wlane = (const char*)(isu ? uw : gw)
      + ((size_t)e * ID + n0 + (wid & 3) * 16 + (lane & 15)) * (size_t)(HD * 4)
      + (size_t)(lane >> 4) * 32;

#define ISSUE_A1(BUFB, KC)                                                      \
  { char* dst_ = sAc + (BUFB) * 49152 + wid * 6144;                             \
    _Pragma("unroll") for (int j = 0; j < 6; ++j)                               \
      load_lds16(aAddr[j] + (KC) * 256, dst_ + j * 1024); }                     \
  FENCE;

#define ISSUE_W1(NXT, KC)                                                       \
  _Pragma("unroll") for (int p = 0; p < 8; ++p)                                 \
    NXT[p] = *(const f32x4*)(wlane + (size_t)(KC) * 512 + (p >> 1) * 128 + (p & 1) * 16); \
  FENCE;

#define COMP1(CUR, BUFB)                                                        \
  { const char* rb_ = sAc + (BUFB) * 49152;                                     \
    bf16x8 bf_[4];                                                              \
    _Pragma("unroll") for (int ks = 0; ks < 4; ++ks)                            \
      bf_[ks] = cvt8(CUR[2 * ks], CUR[2 * ks + 1]);                             \
    _Pragma("unroll") for (int ks = 0; ks < 4; ++ks) {                          \
      const int K_ = ks * 4 + (lane >> 4);                                      \
      _Pragma("unroll") for (int g = 0; g < 12; ++g) if (g * 16 < rem) {        \
        const int tok_ = g * 16 + (lane & 15);                                  \
        bf16x8 aF_ = *(const bf16x8*)(rb_ + tok_ * 256 + ((K_ ^ (tok_ & 7)) << 4)); \
        acc[g] = __builtin_amdgcn_mfma_f32_16x16x32_bf16(aF_, bf_[ks], acc[g], 0, 0, 0); } } }

#define STEP1(KC, CUR, NXT)                                                     \
  ISSUE_A1(((KC) + 1) & 1, (KC) + 1)                                            \
  ISSUE_W1(NXT, (KC) + 1)                                                       \
  COMP1(CUR, (KC) & 1)                                                          \
  LGKM0; SCHED0; VMC("8"); BAR();

  for (int m0 = 0; m0 < n_e; m0 += 192) {
    __syncthreads();
    if (tid < 192) sSlot[tid] = (m0 + tid < n_e) ? lists[e * T_TOK + m0 + tid] : 0;
    __syncthreads();
    const int rem = (n_e - m0 < 192) ? (n_e - m0) : 192;

    // per-lane A source bases (pre-swizzled chunk -> linear LDS dst)
    const char* aAddr[6];
    #pragma unroll
    for (int j = 0; j < 6; ++j) {
      int tok = wid * 24 + j * 4 + (lane >> 4);
      int sl = sSlot[tok];
      aAddr[j] = xbp + (size_t)(sl >> 3) * 4096 + (((lane & 15) ^ (tok & 7)) << 4);
    }

    f32x4 acc[12];
    #pragma unroll
    for (int g = 0; g < 12; ++g) acc[g] = (f32x4){0.f, 0.f, 0.f, 0.f};
    f32x4 wA[8], wB[8];

    // prologue: A(0), W(0); A drained, W free-flying
    ISSUE_A1(0, 0)
    ISSUE_W1(wA, 0)
    VMC("8"); BAR();

    #pragma unroll 1
    for (int it = 0; it < 7; ++it) {      // kc = 0..13
      STEP1(2 * it,     wA, wB)
      STEP1(2 * it + 1, wB, wA)
    }
    STEP1(14, wA, wB)                     // kc = 14 (issues 15)
    COMP1(wB, 1)                          // kc = 15 (no issue)

    // epilogue: u-waves publish acc via LDS; g-waves combine silu(g)*u
    if (isu) {
      #pragma unroll
      for (int g = 0; g < 12; ++g) if (g * 16 < rem)
        #pragma unroll
        for (int j = 0; j < 4; ++j) {
          int tok = g * 16 + (lane >> 4) * 4 + j;
          int cl = (wid & 3) * 16 + (lane & 15);
          *(float*)(sAc + tok * 256 + ((cl ^ ((tok & 3) << 4)) << 2)) = acc[g][j];
        }
    }
    __syncthreads();
    if (!isu) {
      #pragma unroll
      for (int g = 0; g < 12; ++g) if (g * 16 < rem)
        #pragma unroll
        for (int j = 0; j < 4; ++j) {
          int tok = g * 16 + (lane >> 4) * 4 + j;
          if (tok < rem) {
            int cl = (wid & 3) * 16 + (lane & 15);
            float uv = *(const float*)(sAc + tok * 256 + ((cl ^ ((tok & 3) << 4)) << 2));
            float gv = acc[g][j];
            int s = sSlot[tok];
            float hv = (gv / (1.0f + expf(-gv))) * uv;
            hb[(size_t)s * ID + (size_t)(n0 + cl)] = (__bf16)hv;
          }
        }
    }
    __syncthreads();
  }
#undef STEP1
#undef COMP1
#undef ISSUE_W1
#undef ISSUE_A1
}

// ---------------------------------------------------------------------------
// GEMM2: block = (expert, 128 H-cols). M=192, K=768, BK=128 (6 steps).
// Same structure: A dbuf LDS, per-wave 16-row K-major W streaming to regs.
// Weighted atomic scatter to out.
// ---------------------------------------------------------------------------
__global__ __launch_bounds__(512, 2) void gemm2_kernel(
    const unsigned short* __restrict__ hb_u,
    const float* __restrict__ dw,
    const int* __restrict__ counts, const int* __restrict__ lists,
    const float* __restrict__ tw,
    float* __restrict__ out)
{
  __shared__ __bf16 sA[2][24576];
  __shared__ int    sSlot[192];

  const char* hbp = (const char*)hb_u;
  char* sAc = (char*)&sA[0][0];

  // 1024 blocks = 8 XCD chunks of 128 (16 n-tiles x 8 experts)
  const int wg  = blockIdx.x;
  const int idx = wg >> 3;
  const int e   = (wg & 7) * 8 + idx / 16;
  const int n0  = (idx % 16) * 128;
  const int tid = threadIdx.x, wid = tid >> 6, lane = tid & 63;
  const int n_e = counts[e];

  const char* wlane = (const char*)dw
      + ((size_t)e * HD + n0 + wid * 16 + (lane & 15)) * (size_t)(ID * 4)
      + (size_t)(lane >> 4) * 32;

#define ISSUE_A2(BUFB, KC)                                                      \
  { char* dst_ = sAc + (BUFB) * 49152 + wid * 6144;                             \
    _Pragma("unroll") for (int j = 0; j < 6; ++j)                               \
      load_lds16(aAddr[j] + (KC) * 256, dst_ + j * 1024); }                     \
  FENCE;

#define ISSUE_W2(NXT, KC)                                                       \
  _Pragma("unroll") for (int p = 0; p < 8; ++p)                                 \
    NXT[p] = *(const f32x4*)(wlane + (size_t)(KC) * 512 + (p >> 1) * 128 + (p & 1) * 16); \
  FENCE;

#define COMP2(CUR, BUFB)                                                        \
  { const char* rb_ = sAc + (BUFB) * 49152;                                     \
    bf16x8 bf_[4];                                                              \
    _Pragma("unroll") for (int ks = 0; ks < 4; ++ks)                            \
      bf_[ks] = cvt8(CUR[2 * ks], CUR[2 * ks + 1]);                             \
    _Pragma("unroll") for (int ks = 0; ks < 4; ++ks) {                          \
      const int K_ = ks * 4 + (lane >> 4);                                      \
      _Pragma("unroll") for (int g = 0; g < 12; ++g) if (g * 16 < rem) {        \
        const int tok_ = g * 16 + (lane & 15);                                  \
        bf16x8 aF_ = *(const bf16x8*)(rb_ + tok_ * 256 + ((K_ ^ (tok_ & 7)) << 4)); \
        acc[g] = __builtin_amdgcn_mfma_f32_16x16x32_bf16(aF_, bf_[ks], acc[g], 0, 0, 0); } } }

#define STEP2(KC, CUR, NXT)                                                     \
  ISSUE_A2(((KC) + 1) & 1, (KC) + 1)                                            \
  ISSUE_W2(NXT, (KC) + 1)                                                       \
  COMP2(CUR, (KC) & 1)                                                          \
  LGKM0; SCHED0; VMC("8"); BAR();

  for (int m0 = 0; m0 < n_e; m0 += 192) {
    __syncthreads();
    if (tid < 192) sSlot[tid] = (m0 + tid < n_e) ? lists[e * T_TOK + m0 + tid] : 0;
    __syncthreads();
    const int rem = (n_e - m0 < 192) ? (n_e - m0) : 192;

    const char* aAddr[6];
    #pragma unroll
    for (int j = 0; j < 6; ++j) {
      int tok = wid * 24 + j * 4 + (lane >> 4);
      int sl = sSlot[tok];
      aAddr[j] = hbp + (size_t)sl * 1536 + (((lane & 15) ^ (tok & 7)) << 4);
    }

    f32x4 acc[12];
    #pragma unroll
    for (int g = 0; g < 12; ++g) acc[g] = (f32x4){0.f, 0.f, 0.f, 0.f};
    f32x4 wA[8], wB[8];

    ISSUE_A2(0, 0)
    ISSUE_W2(wA, 0)
    VMC("8"); BAR();

    #pragma unroll 1
    for (int it = 0; it < 2; ++it) {      // kc = 0..3
      STEP2(2 * it,     wA, wB)
      STEP2(2 * it + 1, wB, wA)
    }
    STEP2(4, wA, wB)                      // kc = 4 (issues 5)
    COMP2(wB, 1)                          // kc = 5

    // epilogue: weighted atomic scatter
    #pragma unroll
    for (int g = 0; g < 12; ++g) if (g * 16 < rem)
      #pragma unroll
      for (int j = 0; j < 4; ++j) {
        int tok = g * 16 + (lane >> 4) * 4 + j;
        if (tok < rem) {
          int s = sSlot[tok];
          float w = tw[s];
          atomicAdd(out + (size_t)(s >> 3) * HD + (size_t)(n0 + wid * 16 + (lane & 15)),
                    w * acc[g][j]);
        }
      }
  }
#undef STEP2
#undef COMP2
#undef ISSUE_W2
#undef ISSUE_A2
}

// ---------------------------------------------------------------------------
// Launcher. ws: xb bf16 | tw | counts | lists | hidden_buf bf16 (~17 MB).
// ---------------------------------------------------------------------------
extern "C" void kernel_launch(void* const* d_in, const int* in_sizes, int n_in,
                              void* d_out, int out_size, void* d_ws, size_t ws_size,
                              hipStream_t stream) {
  const float* x  = (const float*)d_in[0];
  const float* rw = (const float*)d_in[1];
  const float* gw = (const float*)d_in[2];
  const float* uw = (const float*)d_in[3];
  const float* dw = (const float*)d_in[4];
  float* out = (float*)d_out;

  char* ws = (char*)d_ws;
  const size_t XB_OFF  = 0;
  const size_t TW_OFF  = XB_OFF + (size_t)T_TOK * HD * 2;
  const size_t CNT_OFF = TW_OFF + (size_t)T_TOK * TOPK * 4;
  const size_t LST_OFF = CNT_OFF + 256;
  const size_t HB_OFF  = LST_OFF + (size_t)NE * T_TOK * 4;

  unsigned short* xb  = (unsigned short*)(ws + XB_OFF);
  float*          tw  = (float*)(ws + TW_OFF);
  int*            cnt = (int*)(ws + CNT_OFF);
  int*            lst = (int*)(ws + LST_OFF);
  unsigned short* hb  = (unsigned short*)(ws + HB_OFF);

  hipMemsetAsync(cnt, 0, 256, stream);
  hipMemsetAsync(d_out, 0, (size_t)T_TOK * HD * sizeof(float), stream);

  router_kernel<<<T_TOK, 256, 0, stream>>>(x, rw, xb, tw, cnt, lst);
  gemm1_kernel<<<768, 512, 0, stream>>>(xb, gw, uw, cnt, lst, hb);
  gemm2_kernel<<<1024, 512, 0, stream>>>(hb, dw, cnt, lst, tw, out);
}